// Round 5
// baseline (14.825 us; speedup 1.0000x reference)
//
#include <hip/hip_runtime.h>
#include <math.h>

// Problem constants: B=128, L=4096, FILTER=2, OL=4095, 10 classes.
#define BATCH 128
#define LEN   4096
#define OL    4095
#define NC    10
#define PADI  4096   // window dim padded to 4096 (WC[c][4095] = 0)
#define TPB   1024

// Closed form (derived R0, verified absmax 0.0):
//   g[b,i] = cos(x[b,i,1]) * cos(x[b,i+1,0]) * cos(x[b,i+1,1])
//   Ck = cos(p[k,1]) * cos(p[k,2]) * cos(p[k,3])
//   logits[b,c] = sum_i g[b,i] * (C0*W[2i,c] + C1*W[2i+1,c]) + bias[c]
//
// R5: fold + transpose W once into WC[c][i] = C0*W[2i,c] + C1*W[2i+1,c]
// so the main kernel's weight reads are fully coalesced float4s
// (fixes the 80-160B-lane-stride L1-transaction bottleneck present in R1-R4).

__global__ __launch_bounds__(256) void qcnn_prep(
    const float* __restrict__ W,        // (OL*2, 10)
    const float* __restrict__ params,   // (2, 1, 4) flat
    float* __restrict__ WC)             // (NC, PADI)
{
    const int v = blockIdx.x * 256 + threadIdx.x;  // grid exactly NC*PADI threads
    const int c = v >> 12;         // v / 4096
    const int i = v & (PADI - 1);  // v % 4096

    const float C0 = __cosf(params[1]) * __cosf(params[2]) * __cosf(params[3]);
    const float C1 = __cosf(params[5]) * __cosf(params[6]) * __cosf(params[7]);

    float val = 0.0f;
    if (i < OL)
        val = fmaf(C0, W[20 * i + c], C1 * W[20 * i + 10 + c]);
    WC[v] = val;
}

__global__ __launch_bounds__(TPB) void qcnn_main(
    const float* __restrict__ inputs,   // (B, L, 2)
    const float* __restrict__ WC,       // (NC, PADI)
    const float* __restrict__ bias,     // (10,)
    float* __restrict__ out)            // (B, 10)
{
    const int b = blockIdx.x;
    const int q = threadIdx.x;          // quad index: windows 4q .. 4q+3

    const float* __restrict__ xrow = inputs + (size_t)b * (LEN * 2);
    const int base = 8 * q;

    // windows 4q+k use x[8q+2k+1 .. 8q+2k+3]; need x[8q+1 .. 8q+9]
    const float4 xv0 = *(const float4*)(xrow + base);       // x[8q..8q+3]
    const float4 xv1 = *(const float4*)(xrow + base + 4);   // x[8q+4..8q+7]
    float2 xv2 = make_float2(0.0f, 0.0f);
    if (q < TPB - 1) xv2 = *(const float2*)(xrow + base + 8);  // x[8q+8..8q+9]

    const float c1 = __cosf(xv0.y), c2 = __cosf(xv0.z), c3 = __cosf(xv0.w);
    const float c4 = __cosf(xv1.x), c5 = __cosf(xv1.y), c6 = __cosf(xv1.z), c7 = __cosf(xv1.w);
    const float c8 = __cosf(xv2.x), c9 = __cosf(xv2.y);

    const float g0 = c1 * c2 * c3;
    const float g1 = c3 * c4 * c5;
    const float g2 = c5 * c6 * c7;
    const float g3 = c7 * c8 * c9;   // window 4q+3; for q=1023 WC pad row is 0

    float acc[NC];
#pragma unroll
    for (int c = 0; c < NC; ++c) {
        // coalesced: lane stride 16 B within the wave
        const float4 w = *(const float4*)(WC + (size_t)c * PADI + 4 * q);
        acc[c] = fmaf(g0, w.x, fmaf(g1, w.y, fmaf(g2, w.z, g3 * w.w)));
    }

    // Wave butterfly reduce each of the 10 accumulators.
#pragma unroll
    for (int c = 0; c < NC; ++c) {
        float v = acc[c];
#pragma unroll
        for (int off = 32; off > 0; off >>= 1)
            v += __shfl_xor(v, off, 64);
        acc[c] = v;
    }

    __shared__ float red[TPB / 64][NC];
    const int lane = q & 63;
    const int wave = q >> 6;
    if (lane == 0) {
#pragma unroll
        for (int c = 0; c < NC; ++c) red[wave][c] = acc[c];
    }
    __syncthreads();

    __shared__ float logits_s[NC];
    if (q < NC) {
        float v = bias[q];
#pragma unroll
        for (int k = 0; k < TPB / 64; ++k) v += red[k][q];
        logits_s[q] = v;
    }
    __syncthreads();

    if (q == 0) {
        float logits[NC];
        float m = -1e30f;
#pragma unroll
        for (int c = 0; c < NC; ++c) { logits[c] = logits_s[c]; m = fmaxf(m, logits[c]); }
        float s = 0.0f;
#pragma unroll
        for (int c = 0; c < NC; ++c) { logits[c] = __expf(logits[c] - m); s += logits[c]; }
        const float inv = 1.0f / s;
#pragma unroll
        for (int c = 0; c < NC; ++c) out[b * NC + c] = logits[c] * inv;
    }
}

extern "C" void kernel_launch(void* const* d_in, const int* in_sizes, int n_in,
                              void* d_out, int out_size, void* d_ws, size_t ws_size,
                              hipStream_t stream) {
    const float* inputs = (const float*)d_in[0];  // (128, 4096, 2) f32
    const float* params = (const float*)d_in[1];  // (2, 1, 4) f32
    const float* W      = (const float*)d_in[2];  // (8190, 10) f32
    const float* bias   = (const float*)d_in[3];  // (10,) f32
    float* out          = (float*)d_out;          // (128, 10) f32
    float* WC           = (float*)d_ws;           // (10, 4096) f32 = 160 KB

    qcnn_prep<<<(NC * PADI) / 256, 256, 0, stream>>>(W, params, WC);
    qcnn_main<<<BATCH, TPB, 0, stream>>>(inputs, WC, bias, out);
}

// Round 6
// 11.781 us; speedup vs baseline: 1.2584x; 1.2584x over previous
//
#include <hip/hip_runtime.h>
#include <math.h>

// Problem constants: B=128, L=4096, FILTER=2, OL=4095, 10 classes.
#define BATCH 128
#define LEN   4096
#define OL    4095
#define NC    10
#define TPB   1024
#define NPAIR 2048   // window pairs (2j, 2j+1); j=2047 has only window 4094

// Closed form (derived R0, verified absmax 0.0):
//   g[b,i] = cos(x[b,i,1]) * cos(x[b,i+1,0]) * cos(x[b,i+1,1])
//   Ck = cos(p[k,1]) * cos(p[k,2]) * cos(p[k,3])
//   logits[b,c] = sum_i g[b,i] * (C0*W[2i,c] + C1*W[2i+1,c]) + bias[c]
//   out = softmax(logits)
//
// R6: single launch (launch floor ~10.5us dominates; extra launches cost
// +2.4us each, measured R5). Interior change: replace the 10x6-step wave
// butterfly (~120 VALU/thread) with an LDS transpose-reduce
// (10 conflict-free ds_writes/thread + strided sum on 640 threads).
__global__ __launch_bounds__(TPB) void qcnn_fused(
    const float* __restrict__ inputs,   // (B, L, 2)
    const float* __restrict__ params,   // (2, 1, 4) flat
    const float* __restrict__ W,        // (OL*2, 10)
    const float* __restrict__ bias,     // (10,)
    float* __restrict__ out)            // (B, 10)
{
    const int b   = blockIdx.x;
    const int tid = threadIdx.x;

    const float* __restrict__ xrow = inputs + (size_t)b * (LEN * 2);

    float acc0[NC], acc1[NC];
#pragma unroll
    for (int c = 0; c < NC; ++c) { acc0[c] = 0.0f; acc1[c] = 0.0f; }

#pragma unroll
    for (int k = 0; k < NPAIR / TPB; ++k) {
        const int j  = k * TPB + tid;       // pair index, windows i0=2j, i1=2j+1
        const int i0 = 2 * j;

        const float4 X = *(const float4*)(xrow + 4 * j);   // x[4j..4j+3], 16B aligned
        const float cy = __cosf(X.y);
        const float cz = __cosf(X.z);
        const float cw = __cosf(X.w);
        const float g0 = cy * cz * cw;

        {   // window i0: 20 contiguous floats at W + 20*i0
            const float4* __restrict__ wv = (const float4*)(W + (size_t)i0 * 20);
            const float4 q0 = wv[0], q1 = wv[1], q2 = wv[2], q3 = wv[3], q4 = wv[4];
            acc0[0] = fmaf(g0, q0.x, acc0[0]);  acc0[1] = fmaf(g0, q0.y, acc0[1]);
            acc0[2] = fmaf(g0, q0.z, acc0[2]);  acc0[3] = fmaf(g0, q0.w, acc0[3]);
            acc0[4] = fmaf(g0, q1.x, acc0[4]);  acc0[5] = fmaf(g0, q1.y, acc0[5]);
            acc0[6] = fmaf(g0, q1.z, acc0[6]);  acc0[7] = fmaf(g0, q1.w, acc0[7]);
            acc0[8] = fmaf(g0, q2.x, acc0[8]);  acc0[9] = fmaf(g0, q2.y, acc0[9]);
            acc1[0] = fmaf(g0, q2.z, acc1[0]);  acc1[1] = fmaf(g0, q2.w, acc1[1]);
            acc1[2] = fmaf(g0, q3.x, acc1[2]);  acc1[3] = fmaf(g0, q3.y, acc1[3]);
            acc1[4] = fmaf(g0, q3.z, acc1[4]);  acc1[5] = fmaf(g0, q3.w, acc1[5]);
            acc1[6] = fmaf(g0, q4.x, acc1[6]);  acc1[7] = fmaf(g0, q4.y, acc1[7]);
            acc1[8] = fmaf(g0, q4.z, acc1[8]);  acc1[9] = fmaf(g0, q4.w, acc1[9]);
        }

        if (j < NPAIR - 1) {                 // window i1 = 2j+1 (skip only j=2047)
            const float2 Y = *(const float2*)(xrow + 4 * j + 4);
            const float g1 = cw * __cosf(Y.x) * __cosf(Y.y);
            const float4* __restrict__ wv = (const float4*)(W + (size_t)(i0 + 1) * 20);
            const float4 q0 = wv[0], q1 = wv[1], q2 = wv[2], q3 = wv[3], q4 = wv[4];
            acc0[0] = fmaf(g1, q0.x, acc0[0]);  acc0[1] = fmaf(g1, q0.y, acc0[1]);
            acc0[2] = fmaf(g1, q0.z, acc0[2]);  acc0[3] = fmaf(g1, q0.w, acc0[3]);
            acc0[4] = fmaf(g1, q1.x, acc0[4]);  acc0[5] = fmaf(g1, q1.y, acc0[5]);
            acc0[6] = fmaf(g1, q1.z, acc0[6]);  acc0[7] = fmaf(g1, q1.w, acc0[7]);
            acc0[8] = fmaf(g1, q2.x, acc0[8]);  acc0[9] = fmaf(g1, q2.y, acc0[9]);
            acc1[0] = fmaf(g1, q2.z, acc1[0]);  acc1[1] = fmaf(g1, q2.w, acc1[1]);
            acc1[2] = fmaf(g1, q3.x, acc1[2]);  acc1[3] = fmaf(g1, q3.y, acc1[3]);
            acc1[4] = fmaf(g1, q3.z, acc1[4]);  acc1[5] = fmaf(g1, q3.w, acc1[5]);
            acc1[6] = fmaf(g1, q4.x, acc1[6]);  acc1[7] = fmaf(g1, q4.y, acc1[7]);
            acc1[8] = fmaf(g1, q4.z, acc1[8]);  acc1[9] = fmaf(g1, q4.w, acc1[9]);
        }
    }

    // Fold the two weight-row accumulators with the uniform circuit constants.
    const float C0 = __cosf(params[1]) * __cosf(params[2]) * __cosf(params[3]);
    const float C1 = __cosf(params[5]) * __cosf(params[6]) * __cosf(params[7]);

    // LDS transpose-reduce: sred[c][t] = per-thread partial of class c.
    __shared__ float sred[NC][TPB];       // 40 KB
#pragma unroll
    for (int c = 0; c < NC; ++c)
        sred[c][tid] = fmaf(C1, acc1[c], C0 * acc0[c]);   // consecutive tid -> consecutive banks
    __syncthreads();

    __shared__ float logits_s[NC];
    if (tid < NC * 64) {                  // waves 0..9: one wave per class
        const int c    = tid >> 6;
        const int lane = tid & 63;
        float v = 0.0f;
#pragma unroll
        for (int jj = 0; jj < TPB / 64; ++jj)
            v += sred[c][lane + 64 * jj]; // bank = lane%32: 2-way, free
#pragma unroll
        for (int off = 32; off > 0; off >>= 1)
            v += __shfl_xor(v, off, 64);
        if (lane == 0) logits_s[c] = v + bias[c];
    }
    __syncthreads();

    if (tid == 0) {
        float logits[NC];
        float m = -1e30f;
#pragma unroll
        for (int c = 0; c < NC; ++c) { logits[c] = logits_s[c]; m = fmaxf(m, logits[c]); }
        float s = 0.0f;
#pragma unroll
        for (int c = 0; c < NC; ++c) { logits[c] = __expf(logits[c] - m); s += logits[c]; }
        const float inv = 1.0f / s;
#pragma unroll
        for (int c = 0; c < NC; ++c) out[b * NC + c] = logits[c] * inv;
    }
}

extern "C" void kernel_launch(void* const* d_in, const int* in_sizes, int n_in,
                              void* d_out, int out_size, void* d_ws, size_t ws_size,
                              hipStream_t stream) {
    const float* inputs = (const float*)d_in[0];  // (128, 4096, 2) f32
    const float* params = (const float*)d_in[1];  // (2, 1, 4) f32
    const float* W      = (const float*)d_in[2];  // (8190, 10) f32
    const float* bias   = (const float*)d_in[3];  // (10,) f32
    float* out          = (float*)d_out;          // (128, 10) f32

    qcnn_fused<<<BATCH, TPB, 0, stream>>>(inputs, params, W, bias, out);
}